// Round 12
// baseline (173.419 us; speedup 1.0000x reference)
//
#include <hip/hip_runtime.h>
#include <hip/hip_bf16.h>
#include <hip/hip_fp16.h>
#include <cstdint>

#define HID 64
#define NHEADS 4
#define NEG_SLOPE 0.2f

typedef __attribute__((ext_vector_type(8))) short short8;
typedef __attribute__((ext_vector_type(16))) float f32x16;
typedef unsigned short us;

__device__ __forceinline__ us f2bf(float f) {
    unsigned int u = __float_as_uint(f);
    unsigned int r = (u + 0x7FFFu + ((u >> 16) & 1u)) >> 16;
    return (us)r;
}
__device__ __forceinline__ float bf2f(us h) {
    return __uint_as_float(((unsigned int)h) << 16);
}
__device__ __forceinline__ float leaky(float e) {
    return (e > 0.f) ? e : NEG_SLOPE * e;
}

// ---------------- CSR build ----------------
__global__ void histo_kernel(const int* __restrict__ dst, int* __restrict__ counts, int E) {
    int i = blockIdx.x * blockDim.x + threadIdx.x;
    if (i < E) atomicAdd(&counts[dst[i]], 1);
}

__global__ __launch_bounds__(256) void scanA_kernel(const int* __restrict__ counts,
                                                    int* __restrict__ bsum, int n) {
    const int i = blockIdx.x * 256 + threadIdx.x;
    int v = (i < n) ? counts[i] : 0;
#pragma unroll
    for (int o = 32; o; o >>= 1) v += __shfl_xor(v, o);
    __shared__ int ws[4];
    if ((threadIdx.x & 63) == 0) ws[threadIdx.x >> 6] = v;
    __syncthreads();
    if (threadIdx.x == 0) bsum[blockIdx.x] = ws[0] + ws[1] + ws[2] + ws[3];
}

// scanC: folds the block-sum scan in (each block re-scans bsum in LDS; nb<=256)
__global__ __launch_bounds__(256) void scanC_kernel(const int* __restrict__ counts,
                                                    const int* __restrict__ bsum,
                                                    int* __restrict__ offs,
                                                    int* __restrict__ wp, int n, int nb) {
    __shared__ int sh[256];
    __shared__ int shb[256];
    const int t = threadIdx.x;
    // scan block sums
    shb[t] = (t < nb) ? bsum[t] : 0;
    __syncthreads();
    for (int o = 1; o < 256; o <<= 1) {
        int u = (t >= o) ? shb[t - o] : 0;
        __syncthreads();
        shb[t] += u;
        __syncthreads();
    }
    const int base = (blockIdx.x == 0) ? 0 : shb[blockIdx.x - 1];
    // scan own counts
    const int i = blockIdx.x * 256 + t;
    const int v = (i < n) ? counts[i] : 0;
    sh[t] = v;
    __syncthreads();
    for (int o = 1; o < 256; o <<= 1) {
        int u = (t >= o) ? sh[t - o] : 0;
        __syncthreads();
        sh[t] += u;
        __syncthreads();
    }
    if (i < n) {
        const int off = base + sh[t] - v;
        offs[i] = off;
        wp[i] = off;
        if (i == n - 1) offs[n] = base + sh[t];
    }
}

__global__ void scatter_kernel(const int* __restrict__ src, const int* __restrict__ dst,
                               int* __restrict__ wp, int* __restrict__ csr, int E) {
    int i = blockIdx.x * blockDim.x + threadIdx.x;
    if (i < E) {
        int d = dst[i];
        int p = atomicAdd(&wp[d], 1);
        csr[p] = src[i];
    }
}

// ---------------- prep: W split (3x) + va = W@a precompute (3x) ----------------
__device__ __forceinline__ void wsplit_one(const float* __restrict__ W, us* __restrict__ WTh,
                                           us* __restrict__ WTl, int K, int OUTC, int i) {
    const int c = i / K;
    const int k = i - c * K;
    const float v = W[(size_t)k * OUTC + c];
    const us h = f2bf(v);
    WTh[i] = h;
    WTl[i] = f2bf(v - bf2f(h));
}

__device__ __forceinline__ void vaprep_one(const float* __restrict__ W,
                                           const float* __restrict__ as,
                                           const float* __restrict__ ad,
                                           us* __restrict__ vh, us* __restrict__ vl,
                                           int K, int OUTC, int H, int i) {
    const int j = i / K;
    const int k = i - j * K;
    const int hh = (j < 4) ? j : j - 4;
    const float* a = (j < 4) ? as : ad;
    float acc = 0.f;
    if (hh < H) {
        for (int c = 0; c < 64; ++c)
            acc += W[(size_t)k * OUTC + hh * 64 + c] * a[hh * 64 + c];
    }
    const us h = f2bf(acc);
    vh[i] = h;
    vl[i] = f2bf(acc - bf2f(h));
}

__global__ __launch_bounds__(256) void prep_kernel(
    const float* W1, const float* W2, const float* W3,
    const float* a1s, const float* a1d, const float* a2s, const float* a2d,
    const float* a3s, const float* a3d,
    us* wt1h, us* wt1l, us* wt2h, us* wt2l, us* wt3h, us* wt3l,
    us* va1h, us* va1l, us* va2h, us* va2l, us* va3h, us* va3l) {
    int idx = blockIdx.x * 256 + threadIdx.x;
    if (idx < 16384) { wsplit_one(W1, wt1h, wt1l, 64, 256, idx); return; }
    idx -= 16384;
    if (idx < 65536) { wsplit_one(W2, wt2h, wt2l, 256, 256, idx); return; }
    idx -= 65536;
    if (idx < 16384) { wsplit_one(W3, wt3h, wt3l, 256, 64, idx); return; }
    idx -= 16384;
    if (idx < 512) { vaprep_one(W1, a1s, a1d, va1h, va1l, 64, 256, 4, idx); return; }
    idx -= 512;
    if (idx < 2048) { vaprep_one(W2, a2s, a2d, va2h, va2l, 256, 256, 4, idx); return; }
    idx -= 2048;
    if (idx < 2048) { vaprep_one(W3, a3s, a3d, va3h, va3l, 256, 64, 1, idx); return; }
}

// ---------------- GEMM via MFMA split-bf16 + fused MFMA alpha ----------------
template <int K, int OUTC, int BN, int HA>
__global__ __launch_bounds__(256) void gemm_mfma_kernel(const float* __restrict__ X,
                                                        const us* __restrict__ WTh,
                                                        const us* __restrict__ WTl,
                                                        const us* __restrict__ vah,
                                                        const us* __restrict__ val,
                                                        _Float16* __restrict__ H16,
                                                        float* __restrict__ alpha_s,
                                                        float* __restrict__ alpha_d, int nrows) {
    constexpr int CGS = BN / 64;
    constexpr int NB = BN / 64;
    constexpr int TPC = 4 / NB;
    __shared__ short Ah[64 * 32];
    __shared__ short Al[64 * 32];
    __shared__ short Bh[BN * 32];
    __shared__ short Bl[BN * 32];
    __shared__ short Vh[8 * 32];
    __shared__ short Vl[8 * 32];

    const int tid = threadIdx.x;
    const int lane = tid & 63;
    const int wid = tid >> 6;
    const int wr = wid >> 1;
    const int wc = wid & 1;
    const int r31 = lane & 31;
    const int khw = lane >> 5;
    const int row0 = blockIdx.x * 64;
    const int c0 = blockIdx.y * BN;
    const bool alpha_blk = (blockIdx.y == 0);
    const bool alpha_wave = alpha_blk && (wc == 0);

    const int ar = tid >> 2;
    const int akq = (tid & 3) * 8;
    const int arow = row0 + ar;
    const bool aok = arow < nrows;

    const int bcol = tid / TPC;
    const int bkb = (tid % TPC) * NB;

    f32x16 acc[CGS];
#pragma unroll
    for (int cg = 0; cg < CGS; ++cg)
#pragma unroll
        for (int r = 0; r < 16; ++r) acc[cg][r] = 0.f;
    f32x16 accv;
#pragma unroll
    for (int r = 0; r < 16; ++r) accv[r] = 0.f;

    for (int k0 = 0; k0 < K; k0 += 32) {
        __syncthreads();
        {
            float4 v0 = make_float4(0.f, 0.f, 0.f, 0.f), v1 = v0;
            if (aok) {
                v0 = *reinterpret_cast<const float4*>(&X[(size_t)arow * K + k0 + akq]);
                v1 = *reinterpret_cast<const float4*>(&X[(size_t)arow * K + k0 + akq + 4]);
            }
            float vs[8] = {v0.x, v0.y, v0.z, v0.w, v1.x, v1.y, v1.z, v1.w};
            short8 hi, lo;
#pragma unroll
            for (int j = 0; j < 8; ++j) {
                us h = f2bf(vs[j]);
                hi[j] = (short)h;
                lo[j] = (short)f2bf(vs[j] - bf2f(h));
            }
            const int blk = (akq >> 3) ^ (ar & 3);
            const int off = ar * 32 + (blk << 3);
            *reinterpret_cast<short8*>(&Ah[off]) = hi;
            *reinterpret_cast<short8*>(&Al[off]) = lo;
        }
        {
            const us* srcH = &WTh[(size_t)(c0 + bcol) * K + k0 + bkb * 8];
            const us* srcL = &WTl[(size_t)(c0 + bcol) * K + k0 + bkb * 8];
#pragma unroll
            for (int b = 0; b < NB; ++b) {
                short8 h = *reinterpret_cast<const short8*>(&srcH[b * 8]);
                short8 l = *reinterpret_cast<const short8*>(&srcL[b * 8]);
                const int blk = (bkb + b) ^ (bcol & 3);
                const int off = bcol * 32 + (blk << 3);
                *reinterpret_cast<short8*>(&Bh[off]) = h;
                *reinterpret_cast<short8*>(&Bl[off]) = l;
            }
        }
        if (alpha_blk && tid < 32) {
            const int col = tid >> 2, kb2 = tid & 3;
            *reinterpret_cast<short8*>(&Vh[col * 32 + kb2 * 8]) =
                *reinterpret_cast<const short8*>(&vah[col * K + k0 + kb2 * 8]);
            *reinterpret_cast<short8*>(&Vl[col * 32 + kb2 * 8]) =
                *reinterpret_cast<const short8*>(&val[col * K + k0 + kb2 * 8]);
        }
        __syncthreads();
#pragma unroll
        for (int ks = 0; ks < 32; ks += 16) {
            const int kb = (ks >> 3) + khw;
            const int aoff = (wr * 32 + r31) * 32 + ((kb ^ (r31 & 3)) << 3);
            short8 ah = *reinterpret_cast<const short8*>(&Ah[aoff]);
            short8 al = *reinterpret_cast<const short8*>(&Al[aoff]);
#pragma unroll
            for (int cg = 0; cg < CGS; ++cg) {
                const int coll = wc * (BN / 2) + cg * 32 + r31;
                const int boff = coll * 32 + ((kb ^ (r31 & 3)) << 3);
                short8 bh = *reinterpret_cast<const short8*>(&Bh[boff]);
                short8 bl = *reinterpret_cast<const short8*>(&Bl[boff]);
                acc[cg] = __builtin_amdgcn_mfma_f32_32x32x16_bf16(ah, bh, acc[cg], 0, 0, 0);
                acc[cg] = __builtin_amdgcn_mfma_f32_32x32x16_bf16(ah, bl, acc[cg], 0, 0, 0);
                acc[cg] = __builtin_amdgcn_mfma_f32_32x32x16_bf16(al, bh, acc[cg], 0, 0, 0);
            }
            if (alpha_wave) {
                short8 vh = {}, vl = {};
                if (r31 < 8) {
                    vh = *reinterpret_cast<const short8*>(&Vh[r31 * 32 + (kb << 3)]);
                    vl = *reinterpret_cast<const short8*>(&Vl[r31 * 32 + (kb << 3)]);
                }
                accv = __builtin_amdgcn_mfma_f32_32x32x16_bf16(ah, vh, accv, 0, 0, 0);
                accv = __builtin_amdgcn_mfma_f32_32x32x16_bf16(ah, vl, accv, 0, 0, 0);
                accv = __builtin_amdgcn_mfma_f32_32x32x16_bf16(al, vh, accv, 0, 0, 0);
            }
        }
    }

#pragma unroll
    for (int cg = 0; cg < CGS; ++cg) {
#pragma unroll
        for (int reg = 0; reg < 16; ++reg) {
            const int row = row0 + wr * 32 + (reg & 3) + 8 * (reg >> 2) + 4 * khw;
            if (row < nrows) {
                const int col = c0 + wc * (BN / 2) + cg * 32 + r31;
                H16[(size_t)row * OUTC + col] = (_Float16)acc[cg][reg];
            }
        }
    }
    if (alpha_wave && r31 < 8) {
        const int hsel = r31 & 3;
        if (hsel < HA) {
            float* dstp = (r31 < 4) ? alpha_s : alpha_d;
#pragma unroll
            for (int reg = 0; reg < 16; ++reg) {
                const int row = row0 + wr * 32 + (reg & 3) + 8 * (reg >> 2) + 4 * khw;
                if (row < nrows) dstp[(size_t)row * HA + hsel] = accv[reg];
            }
        }
    }
}

// ---------------- fused segment-softmax + aggregation, 4 heads ----------------
// Block = node, 2 waves; wave hp handles heads {2hp, 2hp+1} (columns hp*128..+127).
// Per edge per wave: one 4B/lane gather (256B) -> 2x gathers in flight per node,
// and 128-thr blocks pack to full 32 waves/CU under the ~16 workgroup/CU cap.
template <bool RELU>
__global__ __launch_bounds__(128) void maxagg4_kernel(const _Float16* __restrict__ h,
                                                      const float* __restrict__ alpha_s,
                                                      const float* __restrict__ alpha_d,
                                                      const int* __restrict__ offs,
                                                      const int* __restrict__ csr,
                                                      float* __restrict__ w,
                                                      const float* __restrict__ bias,
                                                      float* __restrict__ out, int n_nodes) {
    __shared__ float wsh[2][64 * 2];
    const int gw = blockIdx.x;
    const int hp = threadIdx.x >> 6;  // head pair
    const int lane = threadIdx.x & 63;
    if (gw >= n_nodes) return;
    const int start = offs[gw];
    const int end = offs[gw + 1];
    const int deg = end - start;
    const float2 ad = *reinterpret_cast<const float2*>(&alpha_d[(size_t)gw * 4 + hp * 2]);
    const int sub = lane >> 5;        // head within pair
    const int col = hp * 64 + lane;   // half2 column index
    float2 r;
    float2 acc = make_float2(0.f, 0.f);

    if (deg <= 64) {
        const int i = start + lane;
        const bool has = i < end;
        int s_reg = 0;
        float2 e = make_float2(0.f, 0.f);
        float2 m = make_float2(-INFINITY, -INFINITY);
        if (has) {
            s_reg = csr[i];
            const float2 a = *reinterpret_cast<const float2*>(&alpha_s[(size_t)s_reg * 4 + hp * 2]);
            e.x = leaky(a.x + ad.x);
            e.y = leaky(a.y + ad.y);
            m = e;
        }
#pragma unroll
        for (int o = 32; o; o >>= 1) {
            m.x = fmaxf(m.x, __shfl_xor(m.x, o));
            m.y = fmaxf(m.y, __shfl_xor(m.y, o));
        }
        float2 ex = make_float2(0.f, 0.f);
        if (has) {
            ex.x = __expf(e.x - m.x);
            ex.y = __expf(e.y - m.y);
        }
        float2 sum = ex;
#pragma unroll
        for (int o = 32; o; o >>= 1) {
            sum.x += __shfl_xor(sum.x, o);
            sum.y += __shfl_xor(sum.y, o);
        }
        r.x = 1.f / (sum.x + 1e-16f);
        r.y = 1.f / (sum.y + 1e-16f);
        *reinterpret_cast<float2*>(&wsh[hp][lane * 2]) = ex;  // zero-padded, wave-local
        const int degr = (deg + 7) & ~7;
        for (int j = 0; j < degr; j += 8) {
#pragma unroll
            for (int u = 0; u < 8; ++u) {
                const int s = __shfl(s_reg, j + u);
                const float wv = wsh[hp][(j + u) * 2 + sub];
                const unsigned int uv =
                    *reinterpret_cast<const unsigned int*>(&h[(size_t)s * 256 + col * 2]);
                const float2 f = __half22float2(__builtin_bit_cast(__half2, uv));
                acc.x = fmaf(wv, f.x, acc.x);
                acc.y = fmaf(wv, f.y, acc.y);
            }
        }
    } else {
        // slow path (deg > 64): two-phase via global w (each wave owns its float2 half)
        float2 m = make_float2(-INFINITY, -INFINITY);
        float2 sum = make_float2(0.f, 0.f);
        for (int i = start + lane; i < end; i += 64) {
            const int s = csr[i];
            const float2 a = *reinterpret_cast<const float2*>(&alpha_s[(size_t)s * 4 + hp * 2]);
            float2 e;
            e.x = leaky(a.x + ad.x);
            e.y = leaky(a.y + ad.y);
            *reinterpret_cast<float2*>(&w[(size_t)i * 4 + hp * 2]) = e;
            m.x = fmaxf(m.x, e.x);
            m.y = fmaxf(m.y, e.y);
        }
#pragma unroll
        for (int o = 32; o; o >>= 1) {
            m.x = fmaxf(m.x, __shfl_xor(m.x, o));
            m.y = fmaxf(m.y, __shfl_xor(m.y, o));
        }
        for (int i = start + lane; i < end; i += 64) {
            float2 e = *reinterpret_cast<float2*>(&w[(size_t)i * 4 + hp * 2]);
            e.x = __expf(e.x - m.x);
            e.y = __expf(e.y - m.y);
            *reinterpret_cast<float2*>(&w[(size_t)i * 4 + hp * 2]) = e;
            sum.x += e.x;
            sum.y += e.y;
        }
#pragma unroll
        for (int o = 32; o; o >>= 1) {
            sum.x += __shfl_xor(sum.x, o);
            sum.y += __shfl_xor(sum.y, o);
        }
        r.x = 1.f / (sum.x + 1e-16f);
        r.y = 1.f / (sum.y + 1e-16f);
        for (int i = start; i < end; ++i) {
            const int s = csr[i];
            const float2 wv2 = *reinterpret_cast<const float2*>(&w[(size_t)i * 4 + hp * 2]);
            const float wv = sub == 0 ? wv2.x : wv2.y;
            const unsigned int uv =
                *reinterpret_cast<const unsigned int*>(&h[(size_t)s * 256 + col * 2]);
            const float2 f = __half22float2(__builtin_bit_cast(__half2, uv));
            acc.x = fmaf(wv, f.x, acc.x);
            acc.y = fmaf(wv, f.y, acc.y);
        }
    }

    const float rv = sub == 0 ? r.x : r.y;
    const float2 b2 = *reinterpret_cast<const float2*>(&bias[col * 2]);
    float2 o;
    o.x = acc.x * rv + b2.x;
    o.y = acc.y * rv + b2.y;
    if (RELU) {
        o.x = fmaxf(o.x, 0.f);
        o.y = fmaxf(o.y, 0.f);
    }
    *reinterpret_cast<float2*>(&out[(size_t)gw * 256 + col * 2]) = o;
}

// ---------------- fused softmax + aggregation, 1 head (2 nodes per block) ----------------
template <bool RELU>
__global__ __launch_bounds__(128) void maxagg1_kernel(const _Float16* __restrict__ h,
                                                      const float* __restrict__ alpha_s,
                                                      const float* __restrict__ alpha_d,
                                                      const int* __restrict__ offs,
                                                      const int* __restrict__ csr,
                                                      float* __restrict__ w,
                                                      const float* __restrict__ bias,
                                                      float* __restrict__ out, int n_nodes) {
    const int gw = blockIdx.x * 2 + (threadIdx.x >> 6);
    const int lane = threadIdx.x & 63;
    if (gw >= n_nodes) return;
    const int start = offs[gw];
    const int end = offs[gw + 1];
    const int deg = end - start;
    const float ad = alpha_d[gw];
    float r;
    float acc = 0.f;

    if (deg <= 64) {
        const int i = start + lane;
        const bool has = i < end;
        int s_reg = 0;
        float e = 0.f, m = -INFINITY;
        if (has) {
            s_reg = csr[i];
            e = leaky(alpha_s[s_reg] + ad);
            m = e;
        }
#pragma unroll
        for (int o = 32; o; o >>= 1) m = fmaxf(m, __shfl_xor(m, o));
        float ex = has ? __expf(e - m) : 0.f;
        float sum = ex;
#pragma unroll
        for (int o = 32; o; o >>= 1) sum += __shfl_xor(sum, o);
        r = 1.f / (sum + 1e-16f);
        const int degr = (deg + 7) & ~7;
        for (int j = 0; j < degr; j += 8) {
#pragma unroll
            for (int u = 0; u < 8; ++u) {
                const int s = __shfl(s_reg, j + u);
                const float wv = __shfl(ex, j + u);
                acc = fmaf(wv, (float)h[(size_t)s * 64 + lane], acc);
            }
        }
    } else {
        float m = -INFINITY, sum = 0.f;
        for (int i = start + lane; i < end; i += 64) {
            const float e = leaky(alpha_s[csr[i]] + ad);
            w[i] = e;
            m = fmaxf(m, e);
        }
#pragma unroll
        for (int o = 32; o; o >>= 1) m = fmaxf(m, __shfl_xor(m, o));
        for (int i = start + lane; i < end; i += 64) {
            const float ex = __expf(w[i] - m);
            w[i] = ex;
            sum += ex;
        }
#pragma unroll
        for (int o = 32; o; o >>= 1) sum += __shfl_xor(sum, o);
        r = 1.f / (sum + 1e-16f);
        for (int i = start; i < end; ++i)
            acc = fmaf(w[i], (float)h[(size_t)csr[i] * 64 + lane], acc);
    }
    float o = acc * r + bias[lane];
    if (RELU) o = fmaxf(o, 0.f);
    out[(size_t)gw * 64 + lane] = o;
}

// ---------------- launch ----------------
extern "C" void kernel_launch(void* const* d_in, const int* in_sizes, int n_in,
                              void* d_out, int out_size, void* d_ws, size_t ws_size,
                              hipStream_t stream) {
    const float* x   = (const float*)d_in[0];
    const int*   ei  = (const int*)d_in[1];
    const float* W1  = (const float*)d_in[2];
    const float* a1s = (const float*)d_in[3];
    const float* a1d = (const float*)d_in[4];
    const float* b1  = (const float*)d_in[5];
    const float* W2  = (const float*)d_in[6];
    const float* a2s = (const float*)d_in[7];
    const float* a2d = (const float*)d_in[8];
    const float* b2  = (const float*)d_in[9];
    const float* W3  = (const float*)d_in[10];
    const float* a3s = (const float*)d_in[11];
    const float* a3d = (const float*)d_in[12];
    const float* b3  = (const float*)d_in[13];
    float* out = (float*)d_out;

    const int N = in_sizes[0] / HID;
    const int E = in_sizes[1] / 2;
    const int* src = ei;
    const int* dst = ei + E;

    char* p = (char*)d_ws;
    auto alloc = [&](size_t bytes) {
        char* q = p;
        p += (bytes + 255) & ~(size_t)255;
        return q;
    };
    float* bufA = (float*)alloc((size_t)N * 256 * 4);
    float* bufB = (float*)alloc((size_t)N * 256 * 4);
    _Float16* h16 = (_Float16*)alloc((size_t)N * 256 * 2);
    float* alpS = (float*)alloc((size_t)N * NHEADS * 4);
    float* alpD = (float*)alloc((size_t)N * NHEADS * 4);
    float* wbuf = (float*)alloc((size_t)E * NHEADS * 4);
    int* counts = (int*)alloc((size_t)N * 4);
    int* offs   = (int*)alloc((size_t)(N + 1) * 4);
    int* wp     = (int*)alloc((size_t)N * 4);
    int* csr    = (int*)alloc((size_t)E * 4);
    int* bsum   = (int*)alloc((size_t)256 * 4);
    us* wt1h = (us*)alloc((size_t)64 * 256 * 2);
    us* wt1l = (us*)alloc((size_t)64 * 256 * 2);
    us* wt2h = (us*)alloc((size_t)256 * 256 * 2);
    us* wt2l = (us*)alloc((size_t)256 * 256 * 2);
    us* wt3h = (us*)alloc((size_t)256 * 64 * 2);
    us* wt3l = (us*)alloc((size_t)256 * 64 * 2);
    us* va1h = (us*)alloc((size_t)8 * 64 * 2);
    us* va1l = (us*)alloc((size_t)8 * 64 * 2);
    us* va2h = (us*)alloc((size_t)8 * 256 * 2);
    us* va2l = (us*)alloc((size_t)8 * 256 * 2);
    us* va3h = (us*)alloc((size_t)8 * 256 * 2);
    us* va3l = (us*)alloc((size_t)8 * 256 * 2);

    hipMemsetAsync(counts, 0, (size_t)N * 4, stream);
    const int eb = (E + 255) / 256;
    const int nb = (N + 255) / 256;
    histo_kernel<<<eb, 256, 0, stream>>>(dst, counts, E);
    scanA_kernel<<<nb, 256, 0, stream>>>(counts, bsum, N);
    scanC_kernel<<<nb, 256, 0, stream>>>(counts, bsum, offs, wp, N, nb);
    scatter_kernel<<<eb, 256, 0, stream>>>(src, dst, wp, csr, E);

    prep_kernel<<<(102912 + 255) / 256, 256, 0, stream>>>(
        W1, W2, W3, a1s, a1d, a2s, a2d, a3s, a3d,
        wt1h, wt1l, wt2h, wt2l, wt3h, wt3l,
        va1h, va1l, va2h, va2l, va3h, va3l);

    const int gb64 = (N + 63) / 64;

    // layer 1
    gemm_mfma_kernel<64, 256, 128, 4><<<dim3(gb64, 2), 256, 0, stream>>>(
        x, wt1h, wt1l, va1h, va1l, h16, alpS, alpD, N);
    maxagg4_kernel<true><<<N, 128, 0, stream>>>(h16, alpS, alpD, offs, csr, wbuf, b1, bufB, N);

    // layer 2
    gemm_mfma_kernel<256, 256, 128, 4><<<dim3(gb64, 2), 256, 0, stream>>>(
        bufB, wt2h, wt2l, va2h, va2l, h16, alpS, alpD, N);
    maxagg4_kernel<true><<<N, 128, 0, stream>>>(h16, alpS, alpD, offs, csr, wbuf, b2, bufA, N);

    // layer 3
    gemm_mfma_kernel<256, 64, 64, 1><<<dim3(gb64, 1), 256, 0, stream>>>(
        bufA, wt3h, wt3l, va3h, va3l, h16, alpS, alpD, N);
    maxagg1_kernel<false><<<(N + 1) / 2, 128, 0, stream>>>(h16, alpS, alpD, offs, csr, wbuf, b3, out, N);
}

// Round 13
// 166.180 us; speedup vs baseline: 1.0436x; 1.0436x over previous
//
#include <hip/hip_runtime.h>
#include <hip/hip_bf16.h>
#include <hip/hip_fp16.h>
#include <cstdint>

#define HID 64
#define NHEADS 4
#define NEG_SLOPE 0.2f

typedef __attribute__((ext_vector_type(8))) short short8;
typedef __attribute__((ext_vector_type(4))) short short4v;
typedef __attribute__((ext_vector_type(16))) float f32x16;
typedef unsigned short us;

__device__ __forceinline__ us f2bf(float f) {
    unsigned int u = __float_as_uint(f);
    unsigned int r = (u + 0x7FFFu + ((u >> 16) & 1u)) >> 16;
    return (us)r;
}
__device__ __forceinline__ float bf2f(us h) {
    return __uint_as_float(((unsigned int)h) << 16);
}
__device__ __forceinline__ float leaky(float e) {
    return (e > 0.f) ? e : NEG_SLOPE * e;
}

// ---------------- CSR build ----------------
__global__ void histo_kernel(const int* __restrict__ dst, int* __restrict__ counts, int E) {
    int i = blockIdx.x * blockDim.x + threadIdx.x;
    if (i < E) atomicAdd(&counts[dst[i]], 1);
}

__global__ __launch_bounds__(256) void scanA_kernel(const int* __restrict__ counts,
                                                    int* __restrict__ bsum, int n) {
    const int i = blockIdx.x * 256 + threadIdx.x;
    int v = (i < n) ? counts[i] : 0;
#pragma unroll
    for (int o = 32; o; o >>= 1) v += __shfl_xor(v, o);
    __shared__ int ws[4];
    if ((threadIdx.x & 63) == 0) ws[threadIdx.x >> 6] = v;
    __syncthreads();
    if (threadIdx.x == 0) bsum[blockIdx.x] = ws[0] + ws[1] + ws[2] + ws[3];
}

// scanC folds the block-sum scan (nb<=256)
__global__ __launch_bounds__(256) void scanC_kernel(const int* __restrict__ counts,
                                                    const int* __restrict__ bsum,
                                                    int* __restrict__ offs,
                                                    int* __restrict__ wp, int n, int nb) {
    __shared__ int sh[256];
    __shared__ int shb[256];
    const int t = threadIdx.x;
    shb[t] = (t < nb) ? bsum[t] : 0;
    __syncthreads();
    for (int o = 1; o < 256; o <<= 1) {
        int u = (t >= o) ? shb[t - o] : 0;
        __syncthreads();
        shb[t] += u;
        __syncthreads();
    }
    const int base = (blockIdx.x == 0) ? 0 : shb[blockIdx.x - 1];
    const int i = blockIdx.x * 256 + t;
    const int v = (i < n) ? counts[i] : 0;
    sh[t] = v;
    __syncthreads();
    for (int o = 1; o < 256; o <<= 1) {
        int u = (t >= o) ? sh[t - o] : 0;
        __syncthreads();
        sh[t] += u;
        __syncthreads();
    }
    if (i < n) {
        const int off = base + sh[t] - v;
        offs[i] = off;
        wp[i] = off;
        if (i == n - 1) offs[n] = base + sh[t];
    }
}

__global__ void scatter_kernel(const int* __restrict__ src, const int* __restrict__ dst,
                               int* __restrict__ wp, int* __restrict__ csr, int E) {
    int i = blockIdx.x * blockDim.x + threadIdx.x;
    if (i < E) {
        int d = dst[i];
        int p = atomicAdd(&wp[d], 1);
        csr[p] = src[i];
    }
}

// ---------------- prep: x split + W split (3x) + va = W@a (3x) ----------------
__device__ __forceinline__ void wsplit_one(const float* __restrict__ W, us* __restrict__ WTh,
                                           us* __restrict__ WTl, int K, int OUTC, int i) {
    const int c = i / K;
    const int k = i - c * K;
    const float v = W[(size_t)k * OUTC + c];
    const us h = f2bf(v);
    WTh[i] = h;
    WTl[i] = f2bf(v - bf2f(h));
}

__device__ __forceinline__ void vaprep_one(const float* __restrict__ W,
                                           const float* __restrict__ as,
                                           const float* __restrict__ ad,
                                           us* __restrict__ vh, us* __restrict__ vl,
                                           int K, int OUTC, int H, int i) {
    const int j = i / K;
    const int k = i - j * K;
    const int hh = (j < 4) ? j : j - 4;
    const float* a = (j < 4) ? as : ad;
    float acc = 0.f;
    if (hh < H) {
        for (int c = 0; c < 64; ++c)
            acc += W[(size_t)k * OUTC + hh * 64 + c] * a[hh * 64 + c];
    }
    const us h = f2bf(acc);
    vh[i] = h;
    vl[i] = f2bf(acc - bf2f(h));
}

__global__ __launch_bounds__(256) void prep_kernel(
    const float* x, int nx,
    const float* W1, const float* W2, const float* W3,
    const float* a1s, const float* a1d, const float* a2s, const float* a2d,
    const float* a3s, const float* a3d,
    us* xh, us* xl,
    us* wt1h, us* wt1l, us* wt2h, us* wt2l, us* wt3h, us* wt3l,
    us* va1h, us* va1l, us* va2h, us* va2l, us* va3h, us* va3l) {
    int idx = blockIdx.x * 256 + threadIdx.x;
    if (idx < nx) {
        const float v = x[idx];
        const us h = f2bf(v);
        xh[idx] = h;
        xl[idx] = f2bf(v - bf2f(h));
        return;
    }
    idx -= nx;
    if (idx < 16384) { wsplit_one(W1, wt1h, wt1l, 64, 256, idx); return; }
    idx -= 16384;
    if (idx < 65536) { wsplit_one(W2, wt2h, wt2l, 256, 256, idx); return; }
    idx -= 65536;
    if (idx < 16384) { wsplit_one(W3, wt3h, wt3l, 256, 64, idx); return; }
    idx -= 16384;
    if (idx < 512) { vaprep_one(W1, a1s, a1d, va1h, va1l, 64, 256, 4, idx); return; }
    idx -= 512;
    if (idx < 2048) { vaprep_one(W2, a2s, a2d, va2h, va2l, 256, 256, 4, idx); return; }
    idx -= 2048;
    if (idx < 2048) { vaprep_one(W3, a3s, a3d, va3h, va3l, 256, 64, 1, idx); return; }
}

// ---------------- GEMM via MFMA split-bf16 (pre-split A) + fused alpha ----------------
// A and B both pre-split hi/lo bf16, k-contiguous. K-chunk 64 = two 32-k sub-tiles
// (same swizzle per sub-tile). Block tile 64 x BN, 4 waves (2x2).
template <int K, int OUTC, int BN, int HA>
__global__ __launch_bounds__(256) void gemm_mfma_kernel(const us* __restrict__ AH,
                                                        const us* __restrict__ AL,
                                                        const us* __restrict__ WTh,
                                                        const us* __restrict__ WTl,
                                                        const us* __restrict__ vah,
                                                        const us* __restrict__ val,
                                                        _Float16* __restrict__ H16,
                                                        float* __restrict__ alpha_s,
                                                        float* __restrict__ alpha_d, int nrows) {
    constexpr int CGS = BN / 64;
    constexpr int NB = BN / 64;
    constexpr int TPC = 4 / NB;
    __shared__ short Ah[2 * 64 * 32];
    __shared__ short Al[2 * 64 * 32];
    __shared__ short Bh[2 * BN * 32];
    __shared__ short Bl[2 * BN * 32];
    __shared__ short Vh[2 * 8 * 32];
    __shared__ short Vl[2 * 8 * 32];

    const int tid = threadIdx.x;
    const int lane = tid & 63;
    const int wid = tid >> 6;
    const int wr = wid >> 1;
    const int wc = wid & 1;
    const int r31 = lane & 31;
    const int khw = lane >> 5;
    const int row0 = blockIdx.x * 64;
    const int c0 = blockIdx.y * BN;
    const bool alpha_blk = (blockIdx.y == 0);
    const bool alpha_wave = alpha_blk && (wc == 0);

    // A staging: 4 threads/row, one short8 per sub-tile
    const int ar = tid >> 2;
    const int akb = tid & 3;
    const bool aok = (row0 + ar) < nrows;
    // B staging
    const int bcol = tid / TPC;
    const int bkb = (tid % TPC) * NB;

    f32x16 acc[CGS];
#pragma unroll
    for (int cg = 0; cg < CGS; ++cg)
#pragma unroll
        for (int r = 0; r < 16; ++r) acc[cg][r] = 0.f;
    f32x16 accv;
#pragma unroll
    for (int r = 0; r < 16; ++r) accv[r] = 0.f;

    for (int k0 = 0; k0 < K; k0 += 64) {
        __syncthreads();
#pragma unroll
        for (int sub = 0; sub < 2; ++sub) {
            // ---- stage A (copy) ----
            {
                short8 h = {}, l = {};
                if (aok) {
                    const size_t so = (size_t)(row0 + ar) * K + k0 + sub * 32 + akb * 8;
                    h = *reinterpret_cast<const short8*>(&AH[so]);
                    l = *reinterpret_cast<const short8*>(&AL[so]);
                }
                const int off = sub * 2048 + ar * 32 + ((akb ^ (ar & 3)) << 3);
                *reinterpret_cast<short8*>(&Ah[off]) = h;
                *reinterpret_cast<short8*>(&Al[off]) = l;
            }
            // ---- stage B (copy) ----
            {
                const us* srcH = &WTh[(size_t)(c0 + bcol) * K + k0 + sub * 32];
                const us* srcL = &WTl[(size_t)(c0 + bcol) * K + k0 + sub * 32];
#pragma unroll
                for (int b = 0; b < NB; ++b) {
                    short8 h = *reinterpret_cast<const short8*>(&srcH[(bkb + b) * 8]);
                    short8 l = *reinterpret_cast<const short8*>(&srcL[(bkb + b) * 8]);
                    const int off = sub * BN * 32 + bcol * 32 + (((bkb + b) ^ (bcol & 3)) << 3);
                    *reinterpret_cast<short8*>(&Bh[off]) = h;
                    *reinterpret_cast<short8*>(&Bl[off]) = l;
                }
            }
            // ---- stage V ----
            if (alpha_blk && tid < 32) {
                const int col = tid >> 2, kb2 = tid & 3;
                const int off = sub * 256 + col * 32 + kb2 * 8;
                *reinterpret_cast<short8*>(&Vh[off]) =
                    *reinterpret_cast<const short8*>(&vah[col * K + k0 + sub * 32 + kb2 * 8]);
                *reinterpret_cast<short8*>(&Vl[off]) =
                    *reinterpret_cast<const short8*>(&val[col * K + k0 + sub * 32 + kb2 * 8]);
            }
        }
        __syncthreads();
#pragma unroll
        for (int sub = 0; sub < 2; ++sub) {
#pragma unroll
            for (int ks = 0; ks < 32; ks += 16) {
                const int kb = (ks >> 3) + khw;
                const int aoff = sub * 2048 + (wr * 32 + r31) * 32 + ((kb ^ (r31 & 3)) << 3);
                short8 ah = *reinterpret_cast<const short8*>(&Ah[aoff]);
                short8 al = *reinterpret_cast<const short8*>(&Al[aoff]);
#pragma unroll
                for (int cg = 0; cg < CGS; ++cg) {
                    const int coll = wc * (BN / 2) + cg * 32 + r31;
                    const int boff = sub * BN * 32 + coll * 32 + ((kb ^ (r31 & 3)) << 3);
                    short8 bh = *reinterpret_cast<const short8*>(&Bh[boff]);
                    short8 bl = *reinterpret_cast<const short8*>(&Bl[boff]);
                    acc[cg] = __builtin_amdgcn_mfma_f32_32x32x16_bf16(ah, bh, acc[cg], 0, 0, 0);
                    acc[cg] = __builtin_amdgcn_mfma_f32_32x32x16_bf16(ah, bl, acc[cg], 0, 0, 0);
                    acc[cg] = __builtin_amdgcn_mfma_f32_32x32x16_bf16(al, bh, acc[cg], 0, 0, 0);
                }
                if (alpha_wave) {
                    short8 vh = {}, vl = {};
                    if (r31 < 8) {
                        const int voff = sub * 256 + r31 * 32 + (kb << 3);
                        vh = *reinterpret_cast<const short8*>(&Vh[voff]);
                        vl = *reinterpret_cast<const short8*>(&Vl[voff]);
                    }
                    accv = __builtin_amdgcn_mfma_f32_32x32x16_bf16(ah, vh, accv, 0, 0, 0);
                    accv = __builtin_amdgcn_mfma_f32_32x32x16_bf16(ah, vl, accv, 0, 0, 0);
                    accv = __builtin_amdgcn_mfma_f32_32x32x16_bf16(al, vh, accv, 0, 0, 0);
                }
            }
        }
    }

    // epilogue (C/D layout: col=lane&31, row=(reg&3)+8*(reg>>2)+4*(lane>>5))
#pragma unroll
    for (int cg = 0; cg < CGS; ++cg) {
#pragma unroll
        for (int reg = 0; reg < 16; ++reg) {
            const int row = row0 + wr * 32 + (reg & 3) + 8 * (reg >> 2) + 4 * khw;
            if (row < nrows) {
                const int col = c0 + wc * (BN / 2) + cg * 32 + r31;
                H16[(size_t)row * OUTC + col] = (_Float16)acc[cg][reg];
            }
        }
    }
    if (alpha_wave && r31 < 8) {
        const int hsel = r31 & 3;
        if (hsel < HA) {
            float* dstp = (r31 < 4) ? alpha_s : alpha_d;
#pragma unroll
            for (int reg = 0; reg < 16; ++reg) {
                const int row = row0 + wr * 32 + (reg & 3) + 8 * (reg >> 2) + 4 * khw;
                if (row < nrows) dstp[(size_t)row * HA + hsel] = accv[reg];
            }
        }
    }
}

// ---------------- fused segment-softmax + aggregation, 4 heads ----------------
// Round-10 structure (64-thr block, uint2 gathers, 8-edge unroll); output written
// pre-split hi/lo bf16 for the next GEMM's copy-only A-staging.
__global__ __launch_bounds__(64) void maxagg4_kernel(const _Float16* __restrict__ h,
                                                     const float* __restrict__ alpha_s,
                                                     const float* __restrict__ alpha_d,
                                                     const int* __restrict__ offs,
                                                     const int* __restrict__ csr,
                                                     float* __restrict__ w,
                                                     const float* __restrict__ bias,
                                                     us* __restrict__ outH,
                                                     us* __restrict__ outL, int n_nodes) {
    __shared__ float wsh[64 * 4];
    const int gw = blockIdx.x;
    const int lane = threadIdx.x;
    if (gw >= n_nodes) return;
    const int start = offs[gw];
    const int end = offs[gw + 1];
    const int deg = end - start;
    const float4 ad = *reinterpret_cast<const float4*>(&alpha_d[(size_t)gw * 4]);
    const int head = lane >> 4;
    const int cb = lane << 2;
    float4 r;
    float4 acc = make_float4(0.f, 0.f, 0.f, 0.f);

    if (deg <= 64) {
        const int i = start + lane;
        const bool has = i < end;
        int s_reg = 0;
        float4 e = make_float4(0.f, 0.f, 0.f, 0.f);
        float4 m = make_float4(-INFINITY, -INFINITY, -INFINITY, -INFINITY);
        if (has) {
            s_reg = csr[i];
            const float4 a = *reinterpret_cast<const float4*>(&alpha_s[(size_t)s_reg * 4]);
            e.x = leaky(a.x + ad.x);
            e.y = leaky(a.y + ad.y);
            e.z = leaky(a.z + ad.z);
            e.w = leaky(a.w + ad.w);
            m = e;
        }
#pragma unroll
        for (int o = 32; o; o >>= 1) {
            m.x = fmaxf(m.x, __shfl_xor(m.x, o));
            m.y = fmaxf(m.y, __shfl_xor(m.y, o));
            m.z = fmaxf(m.z, __shfl_xor(m.z, o));
            m.w = fmaxf(m.w, __shfl_xor(m.w, o));
        }
        float4 ex = make_float4(0.f, 0.f, 0.f, 0.f);
        if (has) {
            ex.x = __expf(e.x - m.x);
            ex.y = __expf(e.y - m.y);
            ex.z = __expf(e.z - m.z);
            ex.w = __expf(e.w - m.w);
        }
        float4 sum = ex;
#pragma unroll
        for (int o = 32; o; o >>= 1) {
            sum.x += __shfl_xor(sum.x, o);
            sum.y += __shfl_xor(sum.y, o);
            sum.z += __shfl_xor(sum.z, o);
            sum.w += __shfl_xor(sum.w, o);
        }
        r.x = 1.f / (sum.x + 1e-16f);
        r.y = 1.f / (sum.y + 1e-16f);
        r.z = 1.f / (sum.z + 1e-16f);
        r.w = 1.f / (sum.w + 1e-16f);
        *reinterpret_cast<float4*>(&wsh[lane * 4]) = ex;  // zero-padded, wave-local
        const int degr = (deg + 7) & ~7;
        for (int j = 0; j < degr; j += 8) {
#pragma unroll
            for (int u = 0; u < 8; ++u) {
                const int s = __shfl(s_reg, j + u);
                const float wv = wsh[(j + u) * 4 + head];
                const uint2 uv = *reinterpret_cast<const uint2*>(&h[(size_t)s * 256 + cb]);
                const float2 f0 = __half22float2(__builtin_bit_cast(__half2, uv.x));
                const float2 f1 = __half22float2(__builtin_bit_cast(__half2, uv.y));
                acc.x = fmaf(wv, f0.x, acc.x);
                acc.y = fmaf(wv, f0.y, acc.y);
                acc.z = fmaf(wv, f1.x, acc.z);
                acc.w = fmaf(wv, f1.y, acc.w);
            }
        }
    } else {
        float4 m = make_float4(-INFINITY, -INFINITY, -INFINITY, -INFINITY);
        float4 sum = make_float4(0.f, 0.f, 0.f, 0.f);
        for (int i = start + lane; i < end; i += 64) {
            const int s = csr[i];
            const float4 a = *reinterpret_cast<const float4*>(&alpha_s[(size_t)s * 4]);
            float4 e;
            e.x = leaky(a.x + ad.x);
            e.y = leaky(a.y + ad.y);
            e.z = leaky(a.z + ad.z);
            e.w = leaky(a.w + ad.w);
            *reinterpret_cast<float4*>(&w[(size_t)i * 4]) = e;
            m.x = fmaxf(m.x, e.x);
            m.y = fmaxf(m.y, e.y);
            m.z = fmaxf(m.z, e.z);
            m.w = fmaxf(m.w, e.w);
        }
#pragma unroll
        for (int o = 32; o; o >>= 1) {
            m.x = fmaxf(m.x, __shfl_xor(m.x, o));
            m.y = fmaxf(m.y, __shfl_xor(m.y, o));
            m.z = fmaxf(m.z, __shfl_xor(m.z, o));
            m.w = fmaxf(m.w, __shfl_xor(m.w, o));
        }
        for (int i = start + lane; i < end; i += 64) {
            float4 e = *reinterpret_cast<float4*>(&w[(size_t)i * 4]);
            e.x = __expf(e.x - m.x);
            e.y = __expf(e.y - m.y);
            e.z = __expf(e.z - m.z);
            e.w = __expf(e.w - m.w);
            *reinterpret_cast<float4*>(&w[(size_t)i * 4]) = e;
            sum.x += e.x;
            sum.y += e.y;
            sum.z += e.z;
            sum.w += e.w;
        }
#pragma unroll
        for (int o = 32; o; o >>= 1) {
            sum.x += __shfl_xor(sum.x, o);
            sum.y += __shfl_xor(sum.y, o);
            sum.z += __shfl_xor(sum.z, o);
            sum.w += __shfl_xor(sum.w, o);
        }
        r.x = 1.f / (sum.x + 1e-16f);
        r.y = 1.f / (sum.y + 1e-16f);
        r.z = 1.f / (sum.z + 1e-16f);
        r.w = 1.f / (sum.w + 1e-16f);
        for (int i = start; i < end; ++i) {
            const int s = csr[i];
            const float4 w0 = *reinterpret_cast<const float4*>(&w[(size_t)i * 4]);
            const float wv = head == 0 ? w0.x : head == 1 ? w0.y : head == 2 ? w0.z : w0.w;
            const uint2 uv = *reinterpret_cast<const uint2*>(&h[(size_t)s * 256 + cb]);
            const float2 f0 = __half22float2(__builtin_bit_cast(__half2, uv.x));
            const float2 f1 = __half22float2(__builtin_bit_cast(__half2, uv.y));
            acc.x = fmaf(wv, f0.x, acc.x);
            acc.y = fmaf(wv, f0.y, acc.y);
            acc.z = fmaf(wv, f1.x, acc.z);
            acc.w = fmaf(wv, f1.y, acc.w);
        }
    }

    const float rv = head == 0 ? r.x : head == 1 ? r.y : head == 2 ? r.z : r.w;
    const float4 b4 = *reinterpret_cast<const float4*>(&bias[cb]);
    float o0 = fmaxf(acc.x * rv + b4.x, 0.f);
    float o1 = fmaxf(acc.y * rv + b4.y, 0.f);
    float o2 = fmaxf(acc.z * rv + b4.z, 0.f);
    float o3 = fmaxf(acc.w * rv + b4.w, 0.f);
    short4v oh, ol;
    us t;
    t = f2bf(o0); oh[0] = (short)t; ol[0] = (short)f2bf(o0 - bf2f(t));
    t = f2bf(o1); oh[1] = (short)t; ol[1] = (short)f2bf(o1 - bf2f(t));
    t = f2bf(o2); oh[2] = (short)t; ol[2] = (short)f2bf(o2 - bf2f(t));
    t = f2bf(o3); oh[3] = (short)t; ol[3] = (short)f2bf(o3 - bf2f(t));
    *reinterpret_cast<short4v*>(&outH[(size_t)gw * 256 + cb]) = oh;
    *reinterpret_cast<short4v*>(&outL[(size_t)gw * 256 + cb]) = ol;
}

// ---------------- fused softmax + aggregation, 1 head (final, fp32 out) ----------------
__global__ __launch_bounds__(64) void maxagg1_kernel(const _Float16* __restrict__ h,
                                                     const float* __restrict__ alpha_s,
                                                     const float* __restrict__ alpha_d,
                                                     const int* __restrict__ offs,
                                                     const int* __restrict__ csr,
                                                     float* __restrict__ w,
                                                     const float* __restrict__ bias,
                                                     float* __restrict__ out, int n_nodes) {
    const int gw = blockIdx.x;
    const int lane = threadIdx.x;
    if (gw >= n_nodes) return;
    const int start = offs[gw];
    const int end = offs[gw + 1];
    const int deg = end - start;
    const float ad = alpha_d[gw];
    float r;
    float acc = 0.f;

    if (deg <= 64) {
        const int i = start + lane;
        const bool has = i < end;
        int s_reg = 0;
        float e = 0.f, m = -INFINITY;
        if (has) {
            s_reg = csr[i];
            e = leaky(alpha_s[s_reg] + ad);
            m = e;
        }
#pragma unroll
        for (int o = 32; o; o >>= 1) m = fmaxf(m, __shfl_xor(m, o));
        float ex = has ? __expf(e - m) : 0.f;
        float sum = ex;
#pragma unroll
        for (int o = 32; o; o >>= 1) sum += __shfl_xor(sum, o);
        r = 1.f / (sum + 1e-16f);
        const int degr = (deg + 7) & ~7;
        for (int j = 0; j < degr; j += 8) {
#pragma unroll
            for (int u = 0; u < 8; ++u) {
                const int s = __shfl(s_reg, j + u);
                const float wv = __shfl(ex, j + u);
                acc = fmaf(wv, (float)h[(size_t)s * 64 + lane], acc);
            }
        }
    } else {
        float m = -INFINITY, sum = 0.f;
        for (int i = start + lane; i < end; i += 64) {
            const float e = leaky(alpha_s[csr[i]] + ad);
            w[i] = e;
            m = fmaxf(m, e);
        }
#pragma unroll
        for (int o = 32; o; o >>= 1) m = fmaxf(m, __shfl_xor(m, o));
        for (int i = start + lane; i < end; i += 64) {
            const float ex = __expf(w[i] - m);
            w[i] = ex;
            sum += ex;
        }
#pragma unroll
        for (int o = 32; o; o >>= 1) sum += __shfl_xor(sum, o);
        r = 1.f / (sum + 1e-16f);
        for (int i = start; i < end; ++i)
            acc = fmaf(w[i], (float)h[(size_t)csr[i] * 64 + lane], acc);
    }
    float o = acc * r + bias[lane];
    out[(size_t)gw * 64 + lane] = o;
}

// ---------------- launch ----------------
extern "C" void kernel_launch(void* const* d_in, const int* in_sizes, int n_in,
                              void* d_out, int out_size, void* d_ws, size_t ws_size,
                              hipStream_t stream) {
    const float* x   = (const float*)d_in[0];
    const int*   ei  = (const int*)d_in[1];
    const float* W1  = (const float*)d_in[2];
    const float* a1s = (const float*)d_in[3];
    const float* a1d = (const float*)d_in[4];
    const float* b1  = (const float*)d_in[5];
    const float* W2  = (const float*)d_in[6];
    const float* a2s = (const float*)d_in[7];
    const float* a2d = (const float*)d_in[8];
    const float* b2  = (const float*)d_in[9];
    const float* W3  = (const float*)d_in[10];
    const float* a3s = (const float*)d_in[11];
    const float* a3d = (const float*)d_in[12];
    const float* b3  = (const float*)d_in[13];
    float* out = (float*)d_out;

    const int N = in_sizes[0] / HID;
    const int E = in_sizes[1] / 2;
    const int* src = ei;
    const int* dst = ei + E;

    char* p = (char*)d_ws;
    auto alloc = [&](size_t bytes) {
        char* q = p;
        p += (bytes + 255) & ~(size_t)255;
        return q;
    };
    _Float16* h16 = (_Float16*)alloc((size_t)N * 256 * 2);
    us* xh  = (us*)alloc((size_t)N * 64 * 2);
    us* xl  = (us*)alloc((size_t)N * 64 * 2);
    us* g1h = (us*)alloc((size_t)N * 256 * 2);
    us* g1l = (us*)alloc((size_t)N * 256 * 2);
    us* g2h = (us*)alloc((size_t)N * 256 * 2);
    us* g2l = (us*)alloc((size_t)N * 256 * 2);
    float* alpS = (float*)alloc((size_t)N * NHEADS * 4);
    float* alpD = (float*)alloc((size_t)N * NHEADS * 4);
    float* wbuf = (float*)alloc((size_t)E * NHEADS * 4);
    int* counts = (int*)alloc((size_t)N * 4);
    int* offs   = (int*)alloc((size_t)(N + 1) * 4);
    int* wp     = (int*)alloc((size_t)N * 4);
    int* csr    = (int*)alloc((size_t)E * 4);
    int* bsum   = (int*)alloc((size_t)256 * 4);
    us* wt1h = (us*)alloc((size_t)64 * 256 * 2);
    us* wt1l = (us*)alloc((size_t)64 * 256 * 2);
    us* wt2h = (us*)alloc((size_t)256 * 256 * 2);
    us* wt2l = (us*)alloc((size_t)256 * 256 * 2);
    us* wt3h = (us*)alloc((size_t)256 * 64 * 2);
    us* wt3l = (us*)alloc((size_t)256 * 64 * 2);
    us* va1h = (us*)alloc((size_t)8 * 64 * 2);
    us* va1l = (us*)alloc((size_t)8 * 64 * 2);
    us* va2h = (us*)alloc((size_t)8 * 256 * 2);
    us* va2l = (us*)alloc((size_t)8 * 256 * 2);
    us* va3h = (us*)alloc((size_t)8 * 256 * 2);
    us* va3l = (us*)alloc((size_t)8 * 256 * 2);

    hipMemsetAsync(counts, 0, (size_t)N * 4, stream);
    const int eb = (E + 255) / 256;
    const int nb = (N + 255) / 256;
    histo_kernel<<<eb, 256, 0, stream>>>(dst, counts, E);
    scanA_kernel<<<nb, 256, 0, stream>>>(counts, bsum, N);
    scanC_kernel<<<nb, 256, 0, stream>>>(counts, bsum, offs, wp, N, nb);
    scatter_kernel<<<eb, 256, 0, stream>>>(src, dst, wp, csr, E);

    const int nx = N * 64;
    const int ptotal = nx + 102912;
    prep_kernel<<<(ptotal + 255) / 256, 256, 0, stream>>>(
        x, nx, W1, W2, W3, a1s, a1d, a2s, a2d, a3s, a3d,
        xh, xl, wt1h, wt1l, wt2h, wt2l, wt3h, wt3l,
        va1h, va1l, va2h, va2l, va3h, va3l);

    const int gb64 = (N + 63) / 64;

    // layer 1
    gemm_mfma_kernel<64, 256, 128, 4><<<dim3(gb64, 2), 256, 0, stream>>>(
        xh, xl, wt1h, wt1l, va1h, va1l, h16, alpS, alpD, N);
    maxagg4_kernel<<<N, 64, 0, stream>>>(h16, alpS, alpD, offs, csr, wbuf, b1, g1h, g1l, N);

    // layer 2
    gemm_mfma_kernel<256, 256, 128, 4><<<dim3(gb64, 2), 256, 0, stream>>>(
        g1h, g1l, wt2h, wt2l, va2h, va2l, h16, alpS, alpD, N);
    maxagg4_kernel<<<N, 64, 0, stream>>>(h16, alpS, alpD, offs, csr, wbuf, b2, g2h, g2l, N);

    // layer 3
    gemm_mfma_kernel<256, 64, 64, 1><<<dim3(gb64, 1), 256, 0, stream>>>(
        g2h, g2l, wt3h, wt3l, va3h, va3l, h16, alpS, alpD, N);
    maxagg1_kernel<<<N, 64, 0, stream>>>(h16, alpS, alpD, offs, csr, wbuf, b3, out, N);
}